// Round 13
// baseline (1269.127 us; speedup 1.0000x reference)
//
#include <hip/hip_runtime.h>
#include <hip/hip_bf16.h>

typedef unsigned short u16;
typedef short bf16x8 __attribute__((ext_vector_type(8)));
typedef float f32x4 __attribute__((ext_vector_type(4)));
typedef unsigned short u16x8 __attribute__((ext_vector_type(8)));

#define PD 147

static const long OFF_PREAL = 134217728L;
static const long OFF_PRECON= 135421952L;
static const long OFF_WA    = 136626176L;
static const long OFF_WP    = 138723328L;

// raw f4 bf16 NHWC split: elems [0,100663296) (= batches 0..5) at d_out
// u16-offset 167772160 (top 201.3MB of feat region); batches 6,7 in ws f2.
static const long RAW_SPLIT = 100663296L;

__device__ __forceinline__ float lrelu(float v){ return v >= 0.f ? v : 0.01f*v; }

__device__ __forceinline__ float bf2f(u16 u){
    union { unsigned int i; float f; } x; x.i = ((unsigned int)u) << 16; return x.f;
}
__device__ __forceinline__ u16 f2bf(float f){
    __hip_bfloat16 h = __float2bfloat16(f);
    return *reinterpret_cast<u16*>(&h);
}

// ---------------------------------------------------------------------------
// MFMA implicit-GEMM 3x3 SAME conv — LDS-bandwidth-optimized.
// Diagnosis r11/r12: MfmaUtil pinned at 38% across occupancies -> per-CU LDS
// BW bound (wave 64x64 tile = 32 FLOP/LDS-byte < ~45 needed).  Fix: B frags
// are loaded GLOBAL->REGISTERS (weights are L2-resident, same bytes as the
// old LDS path), register-double-buffered with compile-time parity (tap loop
// fully unrolled).  LDS now holds A only -> 64 FLOP/LDS-byte, and the
// per-step barrier disappears (B in regs, A read-only within a cc-chunk):
// barriers drop from 9/cc to 2/cc.  Accumulation order unchanged -> conv
// output bits identical to r12.
// 256 threads / 4 waves, wave = 64px x 64ch, block = 16x16px x 64ch (bz
// splits KOUT).  A reg-staged with fused BN+lrelu of the previous layer.
// Fused deterministic BN partial stats.  Output NHWC bf16 raw; SPLIT:
// batches 0..5 -> out_, 6,7 -> rawhi.
// ---------------------------------------------------------------------------
template<int CIN, int KOUT, bool SPLIT>
__global__ __launch_bounds__(256, 3)
void conv_mfma(const u16* __restrict__ fin, const u16* __restrict__ wt,
               const float* __restrict__ ssin,
               void* __restrict__ out_, u16* __restrict__ rawhi,
               float* __restrict__ part)
{
    constexpr int CC = CIN / 32;
    constexpr int ABYTES = 324 * 32 * 2;           // A tile 18x18x32 bf16
    constexpr int EPIB = 256 * 64 * 2;             // epilogue transpose
    constexpr int SB = ABYTES > EPIB ? ABYTES : EPIB;
    __shared__ __align__(16) char smem[SB];
    u16* As = (u16*)smem;

    const int tid = threadIdx.x;
    const int w = tid >> 6, lane = tid & 63;
    const int tile = blockIdx.x;
    const int tx0 = (tile & 15) << 4, ty0 = (tile >> 4) << 4;
    const int bz = blockIdx.y;                     // output-channel slice
    const int b  = blockIdx.z;
    const long pixbase = (long)b << 16;
    const int hi = lane >> 4;
    const int quarter = tid & 3;

    f32x4 acc[4][4];
#pragma unroll
    for (int m = 0; m < 4; m++)
#pragma unroll
        for (int n = 0; n < 4; n++) acc[m][n] = (f32x4){0.f,0.f,0.f,0.f};

    // A reg-staging: raw bf16 -> BN+lrelu -> bf16 -> per-lane ds_write.
    auto stage_a = [&](int cc){
        float sc8[8], sh8[8];
        int c0 = cc*32 + quarter*8;
#pragma unroll
        for (int j = 0; j < 8; j++){
            sc8[j] = ssin[c0 + j];
            sh8[j] = ssin[CIN + c0 + j];
        }
#pragma unroll
        for (int r = 0; r < 6; ++r){
            int q = r*256 + tid;
            if (q < 1296){
                int pf = q >> 2;
                int ly = pf / 18, lx = pf - ly*18;
                int gy = ty0 + ly - 1, gx = tx0 + lx - 1;
                u16x8 o = (u16x8){0,0,0,0,0,0,0,0};
                if ((unsigned)gy < 256u && (unsigned)gx < 256u){
                    u16x8 v = *(const u16x8*)(fin + ((pixbase + (gy<<8) + gx) * CIN + cc*32 + quarter*8));
#pragma unroll
                    for (int j = 0; j < 8; j++)
                        o[j] = f2bf(lrelu(sc8[j]*bf2f(v[j]) + sh8[j]));
                }
                *(u16x8*)(As + q*8) = o;           // halo stays zero
            }
        }
    };

    // B fragment: direct global->register (weights L2-resident).
    // Same bytes the old LDS path delivered.
    auto load_b = [&](int cc2, int tap, bf16x8* dst){
#pragma unroll
        for (int n = 0; n < 4; n++){
            int ch = bz*64 + n*16 + (lane & 15);
            dst[n] = *(const bf16x8*)(wt + (((long)tap*KOUT + ch) * CIN + cc2*32 + hi*8));
        }
    };

    stage_a(0);
    __syncthreads();

#pragma unroll 1
    for (int cc = 0; cc < CC; ++cc){
        bf16x8 bvreg[2][4];
        load_b(cc, 0, bvreg[0]);
#pragma unroll
        for (int tap = 0; tap < 9; ++tap){
            if (tap + 1 < 9) load_b(cc, tap + 1, bvreg[(tap + 1) & 1]);
            const int dy = tap / 3, dx = tap - dy*3;
            bf16x8 av[4];
#pragma unroll
            for (int m = 0; m < 4; m++){
                int pf = (w*4 + m + dy)*18 + (lane & 15) + dx;
                av[m] = *(const bf16x8*)(As + pf*32 + hi*8);
            }
#pragma unroll
            for (int m = 0; m < 4; m++)
#pragma unroll
                for (int n = 0; n < 4; n++)
                    acc[m][n] = __builtin_amdgcn_mfma_f32_16x16x32_bf16(av[m], bvreg[tap & 1][n], acc[m][n], 0, 0, 0);
        }
        if (cc + 1 < CC){
            __syncthreads();           // all waves done reading A(cc)
            stage_a(cc + 1);
            __syncthreads();           // A(cc+1) visible
        }
    }
    __syncthreads();                    // A reads done before smem reuse

    // ---- fused BN partial stats: 4 wave partials -> LDS -> 64-ch slice ----
    {
        float* sred = (float*)smem;                // [2][4][64], aliases As
#pragma unroll
        for (int n = 0; n < 4; n++){
            float s = 0.f, s2 = 0.f;
#pragma unroll
            for (int m = 0; m < 4; m++)
#pragma unroll
                for (int j = 0; j < 4; j++){
                    float v = acc[m][n][j];
                    s += v; s2 += v*v;
                }
            s += __shfl_down(s, 32); s2 += __shfl_down(s2, 32);
            s += __shfl_down(s, 16); s2 += __shfl_down(s2, 16);
            if (lane < 16){
                int ch = n*16 + lane;
                sred[w*64 + ch]       = s;
                sred[256 + w*64 + ch] = s2;
            }
        }
        __syncthreads();
        if (tid < 64){
            float S = 0.f, S2 = 0.f;
#pragma unroll
            for (int w2 = 0; w2 < 4; w2++){
                S  += sred[w2*64 + tid];
                S2 += sred[256 + w2*64 + tid];
            }
            long i = (long)b*256 + tile;
            long off = (i*KOUT + bz*64 + tid)*2;
            part[off]   = S;
            part[off+1] = S2;
        }
        __syncthreads();
    }

    // ---- epilogue: LDS transpose -> NHWC bf16 raw (64-ch slice) ----
    {
        u16* ep = (u16*)smem;
#pragma unroll
        for (int m = 0; m < 4; m++)
#pragma unroll
            for (int n = 0; n < 4; n++){
                int ch = n*16 + (lane & 15);
#pragma unroll
                for (int j = 0; j < 4; j++){
                    int px = (w*4 + m)*16 + (lane>>4)*4 + j;
                    ep[px*64 + ch] = f2bf(acc[m][n][j]);
                }
            }
        __syncthreads();
        u16* outh = (u16*)out_;
        if (SPLIT && b >= 6) outh = rawhi - RAW_SPLIT;
#pragma unroll
        for (int it = 0; it < 8; ++it){
            int i = it*256 + tid;
            int px = i >> 3, u = i & 7;
            int py = px >> 4, pxc = px & 15;
            long ga = (pixbase + ((ty0+py)<<8) + tx0 + pxc) * KOUT + bz*64 + (long)u*8;
            *(int4*)(outh + ga) = *(int4*)(ep + (long)i*8);
        }
    }
}

// ---------------------------------------------------------------------------
// conv1: 3->32 direct (tiny), output NHWC bf16 raw
// ---------------------------------------------------------------------------
__global__ __launch_bounds__(256)
void conv1_direct(const float* __restrict__ x, const float* __restrict__ w1, u16* __restrict__ f1)
{
    __shared__ float wl[864];
    const int t = threadIdx.x;
    for (int i = t; i < 864; i += 256) wl[i] = w1[i];
    __syncthreads();
    const int y = blockIdx.x, b = blockIdx.y;
    float acc[32];
#pragma unroll
    for (int k = 0; k < 32; k++) acc[k] = 0.f;
    const long ib = (long)b*3*65536;
    for (int c = 0; c < 3; c++){
#pragma unroll
        for (int dy = 0; dy < 3; dy++){
            int gy = y + dy - 1;
#pragma unroll
            for (int dx = 0; dx < 3; dx++){
                int gx = t + dx - 1;
                float v = 0.f;
                if ((unsigned)gy < 256u && (unsigned)gx < 256u)
                    v = x[ib + c*65536 + (gy<<8) + gx];
                const float* wp = &wl[c*9 + dy*3 + dx];
#pragma unroll
                for (int k = 0; k < 32; k++) acc[k] += v * wp[k*27];
            }
        }
    }
    u16 ub[32];
#pragma unroll
    for (int k = 0; k < 32; k++) ub[k] = f2bf(acc[k]);
    u16* dst = f1 + ((long)(b*65536 + (y<<8) + t)) * 32;
#pragma unroll
    for (int j = 0; j < 4; j++) *(int4*)(dst + j*8) = *(int4*)(ub + j*8);
}

// weight transpose: wt[tap][k][c] = bf16(w[k][c][tap])
__global__ __launch_bounds__(256)
void prep_w(const float* __restrict__ w, u16* __restrict__ wt, int K, int C)
{
    int i = blockIdx.x*256 + threadIdx.x;
    if (i >= 9*K*C) return;
    int c = i % C; int r = i / C; int k = r % K; int tap = r / K;
    wt[i] = f2bf(w[((long)k*C + c)*9 + tap]);
}

// ---------------------------------------------------------------------------
// BN stats over NHWC bf16 (layer 1 only)
// ---------------------------------------------------------------------------
template<int C>
__global__ __launch_bounds__(256)
void bn_stats_nhwc(const u16* __restrict__ f, float* __restrict__ part)
{
    constexpr int CQ = C/4;
    constexpr int SUBS = 256/CQ;
    const int t = threadIdx.x;
    const int cq = t & (CQ-1);
    const int sub = t / CQ;
    const long rowbase = (long)blockIdx.x * 512;
    float s[4] = {0,0,0,0}, q2[4] = {0,0,0,0};
    for (int r = sub; r < 512; r += SUBS){
        ushort4 v = *(const ushort4*)(f + (rowbase + r)*C + cq*4);
        float x0 = bf2f(v.x), x1 = bf2f(v.y), x2 = bf2f(v.z), x3 = bf2f(v.w);
        s[0]+=x0; q2[0]+=x0*x0; s[1]+=x1; q2[1]+=x1*x1;
        s[2]+=x2; q2[2]+=x2*x2; s[3]+=x3; q2[3]+=x3*x3;
    }
    __shared__ float r0[256], r1[256];
    for (int j = 0; j < 4; j++){
        r0[t] = s[j]; r1[t] = q2[j];
        __syncthreads();
        for (int st = 128; st >= CQ; st >>= 1){
            if (t < st){ r0[t] += r0[t+st]; r1[t] += r1[t+st]; }
            __syncthreads();
        }
        if (t < CQ){
            part[((long)blockIdx.x * C + t*4 + j)*2]     = r0[t];
            part[((long)blockIdx.x * C + t*4 + j)*2 + 1] = r1[t];
        }
        __syncthreads();
    }
}

__global__ __launch_bounds__(256)
void bn_stats_final2(const float* __restrict__ part, const float* __restrict__ g,
                     const float* __restrict__ bb, int C, int NB2, float* __restrict__ ss)
{
    const int c = blockIdx.x, t = threadIdx.x;
    float s = 0.f, s2 = 0.f;
    for (int i = t; i < NB2; i += 256){
        s  += part[((long)i*C + c)*2];
        s2 += part[((long)i*C + c)*2 + 1];
    }
    __shared__ float r0[256], r1[256];
    r0[t] = s; r1[t] = s2;
    __syncthreads();
    for (int st = 128; st > 0; st >>= 1){
        if (t < st){ r0[t] += r0[t+st]; r1[t] += r1[t+st]; }
        __syncthreads();
    }
    if (t == 0){
        const float invN = 1.f/524288.f;
        float m = r0[0]*invN;
        float v = r1[0]*invN - m*m;
        float sc = g[c]/sqrtf(v + 1e-5f);
        ss[c] = sc; ss[C+c] = bb[c] - m*sc;
    }
}

// ---------------------------------------------------------------------------
// f4 raw NHWC bf16 -> NCHW fp32 feat with BN+lrelu (LDS-tiled transpose).
// 64-px strip per block; 16 consecutive lanes write 16 consecutive float4s
// (256B contiguous) of one channel.
// ---------------------------------------------------------------------------
__global__ __launch_bounds__(256)
void bn_expand_t(const u16* __restrict__ rawlo, const u16* __restrict__ rawhi,
                 const float* __restrict__ ss, float* __restrict__ feat, int b0)
{
    __shared__ u16 lds[64*258];
    const int bid = blockIdx.x;
    const int b = b0 + (bid >> 10);
    const int px0 = (bid & 1023) * 64;
    const long p0 = (((long)(b<<16) + px0)) << 8;
    const u16* src = (b < 6) ? (rawlo + p0) : (rawhi + (p0 - RAW_SPLIT));
    const int t = threadIdx.x;
#pragma unroll
    for (int it = 0; it < 8; ++it){
        int i = it*256 + t;
        int px = i >> 5, u = i & 31;
        *(u16x8*)&lds[px*258 + u*8] = *(const u16x8*)(src + (long)i*8);
    }
    __syncthreads();
#pragma unroll
    for (int it = 0; it < 16; ++it){
        int idx = it*256 + t;
        int ch = idx >> 4;
        int q  = idx & 15;
        const float sc = ss[ch], sh = ss[256 + ch];
        float4 o;
        o.x = lrelu(sc*bf2f(lds[(q*4+0)*258 + ch]) + sh);
        o.y = lrelu(sc*bf2f(lds[(q*4+1)*258 + ch]) + sh);
        o.z = lrelu(sc*bf2f(lds[(q*4+2)*258 + ch]) + sh);
        o.w = lrelu(sc*bf2f(lds[(q*4+3)*258 + ch]) + sh);
        *(float4*)(feat + (((long)(b*256 + ch)) << 16) + px0 + q*4) = o;
    }
}

// ---------------------------------------------------------------------------
// gather W from raw NHWC bf16 + inline BN (matches bn_expand_t arithmetic)
// ---------------------------------------------------------------------------
__global__ __launch_bounds__(256)
void gather_w_raw(const u16* __restrict__ rawlo, const u16* __restrict__ rawhi,
                  const float* __restrict__ ss, const int* __restrict__ hw,
                  float* __restrict__ outW)
{
    const int site = blockIdx.x;
    const int b = site >> 10;
    const int y = hw[site*2], x = hw[site*2 + 1];
    const int c = threadIdx.x;
    const long p = ((long)((b<<16) + (y<<8) + x)) << 8;
    const u16* base = (b < 6) ? (rawlo + p) : (rawhi + (p - RAW_SPLIT));
    float v = bf2f(base[c]);
    outW[(long)site*256 + c] = lrelu(ss[c]*v + ss[256 + c]);
}

__global__ __launch_bounds__(256)
void gather_patch(const float* __restrict__ x, const int* __restrict__ hw,
                  float* __restrict__ out)
{
    const long i = (long)blockIdx.x*256 + threadIdx.x;
    if (i >= 1204224L) return;
    const int px = (int)(i % 7);
    long r = i / 7;
    const int py = (int)(r % 7); r /= 7;
    const int c  = (int)(r % 3); r /= 3;
    const int s  = (int)(r % 1024);
    const int b  = (int)(r / 1024);
    const int site = b*1024 + s;
    const int yy = hw[site*2]     - 3 + py;
    const int xx = hw[site*2 + 1] - 3 + px;
    out[i] = x[(((long)(b*3 + c)) << 16) + ((long)yy << 8) + xx];
}

// ---------------------------------------------------------------------------
// decoder MLP, 8 sites per block (8x weight reuse per load)
// ---------------------------------------------------------------------------
__global__ __launch_bounds__(256)
void mlp8(const float* __restrict__ Wa, const float* __restrict__ l1w,
          const float* __restrict__ l1b, const float* __restrict__ l2w,
          const float* __restrict__ l2b, float* __restrict__ out)
{
    __shared__ float wa[2048];
    __shared__ float h[8][152];
    const int blk = blockIdx.x;
    const int t = threadIdx.x;
#pragma unroll
    for (int it = 0; it < 8; ++it)
        wa[it*256 + t] = Wa[(long)blk*2048 + it*256 + t];
    __syncthreads();
    if (t < PD){
        float a[8] = {0,0,0,0,0,0,0,0};
        const float* wr = l1w + t*256;
#pragma unroll 4
        for (int l = 0; l < 256; ++l){
            float wv = wr[l];
#pragma unroll
            for (int g = 0; g < 8; ++g) a[g] += wa[g*256 + l]*wv;
        }
        float bb = l1b[t];
#pragma unroll
        for (int g = 0; g < 8; ++g) h[g][t] = lrelu(a[g] + bb);
    }
    __syncthreads();
    if (t < PD){
        float r[8] = {0,0,0,0,0,0,0,0};
        const float* wr = l2w + t*PD;
        for (int p = 0; p < PD; ++p){
            float wv = wr[p];
#pragma unroll
            for (int g = 0; g < 8; ++g) r[g] += h[g][p]*wv;
        }
        float bb = l2b[t];
#pragma unroll
        for (int g = 0; g < 8; ++g)
            out[((long)(blk*8 + g))*PD + t] = r[g] + bb;
    }
}

extern "C" void kernel_launch(void* const* d_in, const int* in_sizes, int n_in,
                              void* d_out, int out_size, void* d_ws, size_t ws_size,
                              hipStream_t stream)
{
    const float* x   = (const float*)d_in[0];
    const int*   anc = (const int*)  d_in[1];
    const int*   pos = (const int*)  d_in[2];
    const float* w1  = (const float*)d_in[3];
    const float* g1  = (const float*)d_in[4];
    const float* b1  = (const float*)d_in[5];
    const float* w2  = (const float*)d_in[6];
    const float* g2  = (const float*)d_in[7];
    const float* b2  = (const float*)d_in[8];
    const float* w3  = (const float*)d_in[9];
    const float* g3  = (const float*)d_in[10];
    const float* b3  = (const float*)d_in[11];
    const float* w4  = (const float*)d_in[12];
    const float* g4  = (const float*)d_in[13];
    const float* b4  = (const float*)d_in[14];
    const float* l1w = (const float*)d_in[15];
    const float* l1b = (const float*)d_in[16];
    const float* l2w = (const float*)d_in[17];
    const float* l2b = (const float*)d_in[18];

    float* feat = (float*)d_out;
    float* oPR  = feat + OFF_PREAL;
    float* oRC  = feat + OFF_PRECON;
    float* oWA  = feat + OFF_WA;
    float* oWP  = feat + OFF_WP;

    // ws: f2 [0,64MB), f3 [64MB,192MB), f1 [128MB,160MB) (inside f3, dead before conv3)
    char* wsb = (char*)d_ws;
    u16* f2b = (u16*)wsb;
    u16* f3b = (u16*)(wsb + 67108864L);
    u16* f1b = (u16*)(wsb + 134217728L);

    // raw f4 bf16 NHWC: batches 0..5 in top of feat region; 6,7 in f2 region
    u16* rawlo = (u16*)d_out + 167772160L;    // byte offset 335544320
    u16* rawhi = f2b;                          // f2 dead after conv3

    // scratch inside d_out regions only written by later kernels
    u16* Wt2 = (u16*)oWA;                      // dead after conv2
    u16* Wt3 = Wt2 + 18432;                    // dead after conv3
    u16* Wt4 = Wt3 + 73728;                    // dead after conv4
    float* part = oWP;                         // 2048*256*2 floats max = 4MB
    float* ss1 = oRC, *ss2 = oRC + 64, *ss3 = oRC + 192, *ss4 = oRC + 448;  // dead before mlp8

    prep_w<<<72,   256, 0, stream>>>(w2, Wt2, 64, 32);
    prep_w<<<288,  256, 0, stream>>>(w3, Wt3, 128, 64);
    prep_w<<<1152, 256, 0, stream>>>(w4, Wt4, 256, 128);

    // conv1 -> raw f1; stats on raw f1 -> ss1 (conv2 folds BN into A-staging)
    conv1_direct<<<dim3(256,8), 256, 0, stream>>>(x, w1, f1b);
    bn_stats_nhwc<32><<<1024, 256, 0, stream>>>(f1b, part);
    bn_stats_final2<<<32, 256, 0, stream>>>(part, g1, b1, 32, 1024, ss1);

    conv_mfma<32,64,false><<<dim3(256,1,8), 256, 0, stream>>>(f1b, Wt2, ss1, f2b, nullptr, part);
    bn_stats_final2<<<64, 256, 0, stream>>>(part, g2, b2, 64, 2048, ss2);

    conv_mfma<64,128,false><<<dim3(256,2,8), 256, 0, stream>>>(f2b, Wt3, ss2, f3b, nullptr, part);
    bn_stats_final2<<<128, 256, 0, stream>>>(part, g3, b3, 128, 2048, ss3);

    conv_mfma<128,256,true><<<dim3(256,4,8), 256, 0, stream>>>(f3b, Wt4, ss3, rawlo, rawhi, part);
    bn_stats_final2<<<256, 256, 0, stream>>>(part, g4, b4, 256, 2048, ss4);

    // gathers read RAW f4 (+inline BN) BEFORE the expand kernels clobber raw
    gather_w_raw<<<8192, 256, 0, stream>>>(rawlo, rawhi, ss4, anc, oWA);
    gather_w_raw<<<8192, 256, 0, stream>>>(rawlo, rawhi, ss4, pos, oWP);
    gather_patch<<<4704, 256, 0, stream>>>(x, anc, oPR);

    // expand raw -> fp32 feat (transpose).  Safety by launch order:
    //  E1: b 0..4  writes feat bytes [0, 335.5MB)       (below rawlo)
    //  E2: b 5     writes [335.5, 402.7) = raw of b0,b1 (read by E1)
    //  E3: b 6,7   reads ws, writes [402.7, 537) = raw of b2..b5 (read E1/E2)
    bn_expand_t<<<5120, 256, 0, stream>>>(rawlo, rawhi, ss4, feat, 0);
    bn_expand_t<<<1024, 256, 0, stream>>>(rawlo, rawhi, ss4, feat, 5);
    bn_expand_t<<<2048, 256, 0, stream>>>(rawlo, rawhi, ss4, feat, 6);

    // mlp last: it overwrites oRC (incl. ss slots) after all consumers done
    mlp8<<<1024, 256, 0, stream>>>(oWA, l1w, l1b, l2w, l2b, oRC);
}

// Round 14
// 809.149 us; speedup vs baseline: 1.5685x; 1.5685x over previous
//
#include <hip/hip_runtime.h>
#include <hip/hip_bf16.h>

typedef unsigned short u16;
typedef short bf16x8 __attribute__((ext_vector_type(8)));
typedef float f32x4 __attribute__((ext_vector_type(4)));
typedef unsigned short u16x8 __attribute__((ext_vector_type(8)));

#define PD 147

static const long OFF_PREAL = 134217728L;
static const long OFF_PRECON= 135421952L;
static const long OFF_WA    = 136626176L;
static const long OFF_WP    = 138723328L;

// raw f4 bf16 NHWC split: elems [0,100663296) (= batches 0..5) at d_out
// u16-offset 167772160 (top 201.3MB of feat region); batches 6,7 in ws f2.
static const long RAW_SPLIT = 100663296L;

__device__ __forceinline__ float lrelu(float v){ return v >= 0.f ? v : 0.01f*v; }

__device__ __forceinline__ float bf2f(u16 u){
    union { unsigned int i; float f; } x; x.i = ((unsigned int)u) << 16; return x.f;
}
__device__ __forceinline__ u16 f2bf(float f){
    __hip_bfloat16 h = __float2bfloat16(f);
    return *reinterpret_cast<u16*>(&h);
}

__device__ __forceinline__ void gload16(const void* g, void* l){
    __builtin_amdgcn_global_load_lds((const __attribute__((address_space(1))) void*)g,
                                     (__attribute__((address_space(3))) void*)l, 16, 0, 0);
}

// ---------------------------------------------------------------------------
// MFMA implicit-GEMM 3x3 SAME conv — round-12 structure (proven 766us total)
// + T14 async A-restage split.
// 256 threads / 4 waves, wave = 64px x 64ch (acc 64 VGPR), block = 16x16px x
// 64 output ch (bz splits KOUT); 3 blocks/CU.  B in LDS dbuf via
// global_load_lds (wave-uniform dst, m104); A single-buffered in LDS with
// fused BN+lrelu of the previous layer.
// T14 (r13 change): A(cc+1) global loads are ISSUED AT TAP 0 of chunk cc
// into registers (one tap of MFMA covers the L2 latency before the first
// barrier's vmcnt drain); after the chunk-final barrier only BN+ds_write
// runs.  Removes the serial load window of the restage.  Halo-zero
// semantics identical to r12 (ok-mask on load AND write).
// Fused deterministic BN partial stats.  Output NHWC bf16 raw; SPLIT:
// batches 0..5 -> out_, 6,7 -> rawhi.
// ---------------------------------------------------------------------------
template<int CIN, int KOUT, bool SPLIT>
__global__ __launch_bounds__(256, 3)
void conv_mfma(const u16* __restrict__ fin, const u16* __restrict__ wt,
               const float* __restrict__ ssin,
               void* __restrict__ out_, u16* __restrict__ rawhi,
               float* __restrict__ part)
{
    constexpr int CC = CIN / 32;
    constexpr int NSTEPS = CC * 9;                 // one tap per step
    constexpr int ABYTES = 324 * 32 * 2;           // single-buffered A
    constexpr int BBYTES = 2 * 64 * 32 * 2;        // dbuf B: 64ch x 32 x bf16
    constexpr int EPIB = 256 * 64 * 2;             // epilogue transpose
    constexpr int SB = (ABYTES + BBYTES) > EPIB ? (ABYTES + BBYTES) : EPIB;
    __shared__ __align__(16) char smem[SB];
    u16* As = (u16*)smem;
    u16* Bs = (u16*)(smem + ABYTES);

    const int tid = threadIdx.x;
    const int w = tid >> 6, lane = tid & 63;
    const int tile = blockIdx.x;
    const int tx0 = (tile & 15) << 4, ty0 = (tile >> 4) << 4;
    const int bz = blockIdx.y;                     // output-channel slice
    const int b  = blockIdx.z;
    const long pixbase = (long)b << 16;
    const int hi = lane >> 4;
    const int quarter = tid & 3;

    f32x4 acc[4][4];
#pragma unroll
    for (int m = 0; m < 4; m++)
#pragma unroll
        for (int n = 0; n < 4; n++) acc[m][n] = (f32x4){0.f,0.f,0.f,0.f};

    // T14 split A-staging: load raw bf16 -> regs early; BN+lrelu+ds_write late
    u16x8 areg[6];
    auto load_a = [&](int cc){
#pragma unroll
        for (int r = 0; r < 6; ++r){
            int q = r*256 + tid;
            u16x8 v = (u16x8){0,0,0,0,0,0,0,0};
            if (q < 1296){
                int pf = q >> 2;
                int ly = pf / 18, lx = pf - ly*18;
                int gy = ty0 + ly - 1, gx = tx0 + lx - 1;
                if ((unsigned)gy < 256u && (unsigned)gx < 256u)
                    v = *(const u16x8*)(fin + ((pixbase + (gy<<8) + gx) * CIN + cc*32 + quarter*8));
            }
            areg[r] = v;
        }
    };
    auto write_a = [&](int cc){
        float sc8[8], sh8[8];
        int c0 = cc*32 + quarter*8;
#pragma unroll
        for (int j = 0; j < 8; j++){
            sc8[j] = ssin[c0 + j];
            sh8[j] = ssin[CIN + c0 + j];
        }
#pragma unroll
        for (int r = 0; r < 6; ++r){
            int q = r*256 + tid;
            if (q < 1296){
                int pf = q >> 2;
                int ly = pf / 18, lx = pf - ly*18;
                int gy = ty0 + ly - 1, gx = tx0 + lx - 1;
                u16x8 o = (u16x8){0,0,0,0,0,0,0,0};
                if ((unsigned)gy < 256u && (unsigned)gx < 256u){
#pragma unroll
                    for (int j = 0; j < 8; j++)
                        o[j] = f2bf(lrelu(sc8[j]*bf2f(areg[r][j]) + sh8[j]));
                }
                *(u16x8*)(As + q*8) = o;           // halo stays zero
            }
        }
    };
    // B staging: one gload16 per thread (64ch x 4 quarters = 256 = blockDim)
    auto stage_b = [&](int s, int buf){
        int cc2 = s / 9, tap = s - cc2*9;
        const u16* src = wt + (((long)tap*KOUT + bz*64 + (tid>>2)) * CIN + cc2*32 + (tid&3)*8);
        u16* dst = Bs + buf*2048 + (w*64)*8;       // WAVE-UNIFORM base (m104)
        gload16(src, dst);
    };

    // prologue
    load_a(0);
    write_a(0);
    stage_b(0, 0);
    __syncthreads();

#pragma unroll 1
    for (int s = 0; s < NSTEPS; ++s){
        int cc = s / 9, tap = s - cc*9;
        if (s + 1 < NSTEPS) stage_b(s + 1, (s + 1) & 1);
        if (tap == 0 && cc + 1 < CC) load_a(cc + 1);   // T14: issue early

        int dy = tap / 3, dx = tap - dy*3;
        const u16* Bb = Bs + (s & 1) * 2048;
        bf16x8 av[4];
#pragma unroll
        for (int m = 0; m < 4; m++){
            int pf = (w*4 + m + dy)*18 + (lane & 15) + dx;
            av[m] = *(const bf16x8*)(As + pf*32 + hi*8);
        }
        bf16x8 bv[4];
#pragma unroll
        for (int n = 0; n < 4; n++){
            int chl = n*16 + (lane & 15);
            bv[n] = *(const bf16x8*)(Bb + chl*32 + hi*8);
        }
#pragma unroll
        for (int m = 0; m < 4; m++)
#pragma unroll
            for (int n = 0; n < 4; n++)
                acc[m][n] = __builtin_amdgcn_mfma_f32_16x16x32_bf16(av[m], bv[n], acc[m][n], 0, 0, 0);

        __syncthreads();   // drains vmcnt/lgkmcnt (next B ready) + readers done
        if (tap == 8 && cc + 1 < CC){
            write_a(cc + 1);       // regs already loaded: BN + ds_write only
            __syncthreads();       // A(cc+1) visible before next step
        }
    }

    // ---- fused BN partial stats: 4 wave partials -> LDS -> 64-ch slice ----
    {
        float* sred = (float*)smem;                // [2][4][64], aliases As
#pragma unroll
        for (int n = 0; n < 4; n++){
            float s = 0.f, s2 = 0.f;
#pragma unroll
            for (int m = 0; m < 4; m++)
#pragma unroll
                for (int j = 0; j < 4; j++){
                    float v = acc[m][n][j];
                    s += v; s2 += v*v;
                }
            s += __shfl_down(s, 32); s2 += __shfl_down(s2, 32);
            s += __shfl_down(s, 16); s2 += __shfl_down(s2, 16);
            if (lane < 16){
                int ch = n*16 + lane;
                sred[w*64 + ch]       = s;
                sred[256 + w*64 + ch] = s2;
            }
        }
        __syncthreads();
        if (tid < 64){
            float S = 0.f, S2 = 0.f;
#pragma unroll
            for (int w2 = 0; w2 < 4; w2++){
                S  += sred[w2*64 + tid];
                S2 += sred[256 + w2*64 + tid];
            }
            long i = (long)b*256 + tile;
            long off = (i*KOUT + bz*64 + tid)*2;
            part[off]   = S;
            part[off+1] = S2;
        }
        __syncthreads();
    }

    // ---- epilogue: LDS transpose -> NHWC bf16 raw (64-ch slice) ----
    {
        u16* ep = (u16*)smem;
#pragma unroll
        for (int m = 0; m < 4; m++)
#pragma unroll
            for (int n = 0; n < 4; n++){
                int ch = n*16 + (lane & 15);
#pragma unroll
                for (int j = 0; j < 4; j++){
                    int px = (w*4 + m)*16 + (lane>>4)*4 + j;
                    ep[px*64 + ch] = f2bf(acc[m][n][j]);
                }
            }
        __syncthreads();
        u16* outh = (u16*)out_;
        if (SPLIT && b >= 6) outh = rawhi - RAW_SPLIT;
#pragma unroll
        for (int it = 0; it < 8; ++it){
            int i = it*256 + tid;
            int px = i >> 3, u = i & 7;
            int py = px >> 4, pxc = px & 15;
            long ga = (pixbase + ((ty0+py)<<8) + tx0 + pxc) * KOUT + bz*64 + (long)u*8;
            *(int4*)(outh + ga) = *(int4*)(ep + (long)i*8);
        }
    }
}

// ---------------------------------------------------------------------------
// conv1: 3->32 direct (tiny), output NHWC bf16 raw
// ---------------------------------------------------------------------------
__global__ __launch_bounds__(256)
void conv1_direct(const float* __restrict__ x, const float* __restrict__ w1, u16* __restrict__ f1)
{
    __shared__ float wl[864];
    const int t = threadIdx.x;
    for (int i = t; i < 864; i += 256) wl[i] = w1[i];
    __syncthreads();
    const int y = blockIdx.x, b = blockIdx.y;
    float acc[32];
#pragma unroll
    for (int k = 0; k < 32; k++) acc[k] = 0.f;
    const long ib = (long)b*3*65536;
    for (int c = 0; c < 3; c++){
#pragma unroll
        for (int dy = 0; dy < 3; dy++){
            int gy = y + dy - 1;
#pragma unroll
            for (int dx = 0; dx < 3; dx++){
                int gx = t + dx - 1;
                float v = 0.f;
                if ((unsigned)gy < 256u && (unsigned)gx < 256u)
                    v = x[ib + c*65536 + (gy<<8) + gx];
                const float* wp = &wl[c*9 + dy*3 + dx];
#pragma unroll
                for (int k = 0; k < 32; k++) acc[k] += v * wp[k*27];
            }
        }
    }
    u16 ub[32];
#pragma unroll
    for (int k = 0; k < 32; k++) ub[k] = f2bf(acc[k]);
    u16* dst = f1 + ((long)(b*65536 + (y<<8) + t)) * 32;
#pragma unroll
    for (int j = 0; j < 4; j++) *(int4*)(dst + j*8) = *(int4*)(ub + j*8);
}

// weight transpose: wt[tap][k][c] = bf16(w[k][c][tap])
__global__ __launch_bounds__(256)
void prep_w(const float* __restrict__ w, u16* __restrict__ wt, int K, int C)
{
    int i = blockIdx.x*256 + threadIdx.x;
    if (i >= 9*K*C) return;
    int c = i % C; int r = i / C; int k = r % K; int tap = r / K;
    wt[i] = f2bf(w[((long)k*C + c)*9 + tap]);
}

// ---------------------------------------------------------------------------
// BN stats over NHWC bf16 (layer 1 only)
// ---------------------------------------------------------------------------
template<int C>
__global__ __launch_bounds__(256)
void bn_stats_nhwc(const u16* __restrict__ f, float* __restrict__ part)
{
    constexpr int CQ = C/4;
    constexpr int SUBS = 256/CQ;
    const int t = threadIdx.x;
    const int cq = t & (CQ-1);
    const int sub = t / CQ;
    const long rowbase = (long)blockIdx.x * 512;
    float s[4] = {0,0,0,0}, q2[4] = {0,0,0,0};
    for (int r = sub; r < 512; r += SUBS){
        ushort4 v = *(const ushort4*)(f + (rowbase + r)*C + cq*4);
        float x0 = bf2f(v.x), x1 = bf2f(v.y), x2 = bf2f(v.z), x3 = bf2f(v.w);
        s[0]+=x0; q2[0]+=x0*x0; s[1]+=x1; q2[1]+=x1*x1;
        s[2]+=x2; q2[2]+=x2*x2; s[3]+=x3; q2[3]+=x3*x3;
    }
    __shared__ float r0[256], r1[256];
    for (int j = 0; j < 4; j++){
        r0[t] = s[j]; r1[t] = q2[j];
        __syncthreads();
        for (int st = 128; st >= CQ; st >>= 1){
            if (t < st){ r0[t] += r0[t+st]; r1[t] += r1[t+st]; }
            __syncthreads();
        }
        if (t < CQ){
            part[((long)blockIdx.x * C + t*4 + j)*2]     = r0[t];
            part[((long)blockIdx.x * C + t*4 + j)*2 + 1] = r1[t];
        }
        __syncthreads();
    }
}

__global__ __launch_bounds__(256)
void bn_stats_final2(const float* __restrict__ part, const float* __restrict__ g,
                     const float* __restrict__ bb, int C, int NB2, float* __restrict__ ss)
{
    const int c = blockIdx.x, t = threadIdx.x;
    float s = 0.f, s2 = 0.f;
    for (int i = t; i < NB2; i += 256){
        s  += part[((long)i*C + c)*2];
        s2 += part[((long)i*C + c)*2 + 1];
    }
    __shared__ float r0[256], r1[256];
    r0[t] = s; r1[t] = s2;
    __syncthreads();
    for (int st = 128; st > 0; st >>= 1){
        if (t < st){ r0[t] += r0[t+st]; r1[t] += r1[t+st]; }
        __syncthreads();
    }
    if (t == 0){
        const float invN = 1.f/524288.f;
        float m = r0[0]*invN;
        float v = r1[0]*invN - m*m;
        float sc = g[c]/sqrtf(v + 1e-5f);
        ss[c] = sc; ss[C+c] = bb[c] - m*sc;
    }
}

// ---------------------------------------------------------------------------
// f4 raw NHWC bf16 -> NCHW fp32 feat with BN+lrelu (LDS-tiled transpose).
// 64-px strip per block; 16 consecutive lanes write 16 consecutive float4s
// (256B contiguous) of one channel.
// ---------------------------------------------------------------------------
__global__ __launch_bounds__(256)
void bn_expand_t(const u16* __restrict__ rawlo, const u16* __restrict__ rawhi,
                 const float* __restrict__ ss, float* __restrict__ feat, int b0)
{
    __shared__ u16 lds[64*258];
    const int bid = blockIdx.x;
    const int b = b0 + (bid >> 10);
    const int px0 = (bid & 1023) * 64;
    const long p0 = (((long)(b<<16) + px0)) << 8;
    const u16* src = (b < 6) ? (rawlo + p0) : (rawhi + (p0 - RAW_SPLIT));
    const int t = threadIdx.x;
#pragma unroll
    for (int it = 0; it < 8; ++it){
        int i = it*256 + t;
        int px = i >> 5, u = i & 31;
        *(u16x8*)&lds[px*258 + u*8] = *(const u16x8*)(src + (long)i*8);
    }
    __syncthreads();
#pragma unroll
    for (int it = 0; it < 16; ++it){
        int idx = it*256 + t;
        int ch = idx >> 4;
        int q  = idx & 15;
        const float sc = ss[ch], sh = ss[256 + ch];
        float4 o;
        o.x = lrelu(sc*bf2f(lds[(q*4+0)*258 + ch]) + sh);
        o.y = lrelu(sc*bf2f(lds[(q*4+1)*258 + ch]) + sh);
        o.z = lrelu(sc*bf2f(lds[(q*4+2)*258 + ch]) + sh);
        o.w = lrelu(sc*bf2f(lds[(q*4+3)*258 + ch]) + sh);
        *(float4*)(feat + (((long)(b*256 + ch)) << 16) + px0 + q*4) = o;
    }
}

// ---------------------------------------------------------------------------
// gather W from raw NHWC bf16 + inline BN (matches bn_expand_t arithmetic)
// ---------------------------------------------------------------------------
__global__ __launch_bounds__(256)
void gather_w_raw(const u16* __restrict__ rawlo, const u16* __restrict__ rawhi,
                  const float* __restrict__ ss, const int* __restrict__ hw,
                  float* __restrict__ outW)
{
    const int site = blockIdx.x;
    const int b = site >> 10;
    const int y = hw[site*2], x = hw[site*2 + 1];
    const int c = threadIdx.x;
    const long p = ((long)((b<<16) + (y<<8) + x)) << 8;
    const u16* base = (b < 6) ? (rawlo + p) : (rawhi + (p - RAW_SPLIT));
    float v = bf2f(base[c]);
    outW[(long)site*256 + c] = lrelu(ss[c]*v + ss[256 + c]);
}

__global__ __launch_bounds__(256)
void gather_patch(const float* __restrict__ x, const int* __restrict__ hw,
                  float* __restrict__ out)
{
    const long i = (long)blockIdx.x*256 + threadIdx.x;
    if (i >= 1204224L) return;
    const int px = (int)(i % 7);
    long r = i / 7;
    const int py = (int)(r % 7); r /= 7;
    const int c  = (int)(r % 3); r /= 3;
    const int s  = (int)(r % 1024);
    const int b  = (int)(r / 1024);
    const int site = b*1024 + s;
    const int yy = hw[site*2]     - 3 + py;
    const int xx = hw[site*2 + 1] - 3 + px;
    out[i] = x[(((long)(b*3 + c)) << 16) + ((long)yy << 8) + xx];
}

// ---------------------------------------------------------------------------
// decoder MLP, 8 sites per block (8x weight reuse per load)
// ---------------------------------------------------------------------------
__global__ __launch_bounds__(256)
void mlp8(const float* __restrict__ Wa, const float* __restrict__ l1w,
          const float* __restrict__ l1b, const float* __restrict__ l2w,
          const float* __restrict__ l2b, float* __restrict__ out)
{
    __shared__ float wa[2048];
    __shared__ float h[8][152];
    const int blk = blockIdx.x;
    const int t = threadIdx.x;
#pragma unroll
    for (int it = 0; it < 8; ++it)
        wa[it*256 + t] = Wa[(long)blk*2048 + it*256 + t];
    __syncthreads();
    if (t < PD){
        float a[8] = {0,0,0,0,0,0,0,0};
        const float* wr = l1w + t*256;
#pragma unroll 4
        for (int l = 0; l < 256; ++l){
            float wv = wr[l];
#pragma unroll
            for (int g = 0; g < 8; ++g) a[g] += wa[g*256 + l]*wv;
        }
        float bb = l1b[t];
#pragma unroll
        for (int g = 0; g < 8; ++g) h[g][t] = lrelu(a[g] + bb);
    }
    __syncthreads();
    if (t < PD){
        float r[8] = {0,0,0,0,0,0,0,0};
        const float* wr = l2w + t*PD;
        for (int p = 0; p < PD; ++p){
            float wv = wr[p];
#pragma unroll
            for (int g = 0; g < 8; ++g) r[g] += h[g][p]*wv;
        }
        float bb = l2b[t];
#pragma unroll
        for (int g = 0; g < 8; ++g)
            out[((long)(blk*8 + g))*PD + t] = r[g] + bb;
    }
}

extern "C" void kernel_launch(void* const* d_in, const int* in_sizes, int n_in,
                              void* d_out, int out_size, void* d_ws, size_t ws_size,
                              hipStream_t stream)
{
    const float* x   = (const float*)d_in[0];
    const int*   anc = (const int*)  d_in[1];
    const int*   pos = (const int*)  d_in[2];
    const float* w1  = (const float*)d_in[3];
    const float* g1  = (const float*)d_in[4];
    const float* b1  = (const float*)d_in[5];
    const float* w2  = (const float*)d_in[6];
    const float* g2  = (const float*)d_in[7];
    const float* b2  = (const float*)d_in[8];
    const float* w3  = (const float*)d_in[9];
    const float* g3  = (const float*)d_in[10];
    const float* b3  = (const float*)d_in[11];
    const float* w4  = (const float*)d_in[12];
    const float* g4  = (const float*)d_in[13];
    const float* b4  = (const float*)d_in[14];
    const float* l1w = (const float*)d_in[15];
    const float* l1b = (const float*)d_in[16];
    const float* l2w = (const float*)d_in[17];
    const float* l2b = (const float*)d_in[18];

    float* feat = (float*)d_out;
    float* oPR  = feat + OFF_PREAL;
    float* oRC  = feat + OFF_PRECON;
    float* oWA  = feat + OFF_WA;
    float* oWP  = feat + OFF_WP;

    // ws: f2 [0,64MB), f3 [64MB,192MB), f1 [128MB,160MB) (inside f3, dead before conv3)
    char* wsb = (char*)d_ws;
    u16* f2b = (u16*)wsb;
    u16* f3b = (u16*)(wsb + 67108864L);
    u16* f1b = (u16*)(wsb + 134217728L);

    // raw f4 bf16 NHWC: batches 0..5 in top of feat region; 6,7 in f2 region
    u16* rawlo = (u16*)d_out + 167772160L;    // byte offset 335544320
    u16* rawhi = f2b;                          // f2 dead after conv3

    // scratch inside d_out regions only written by later kernels
    u16* Wt2 = (u16*)oWA;                      // dead after conv2
    u16* Wt3 = Wt2 + 18432;                    // dead after conv3
    u16* Wt4 = Wt3 + 73728;                    // dead after conv4
    float* part = oWP;                         // 2048*256*2 floats max = 4MB
    float* ss1 = oRC, *ss2 = oRC + 64, *ss3 = oRC + 192, *ss4 = oRC + 448;  // dead before mlp8

    prep_w<<<72,   256, 0, stream>>>(w2, Wt2, 64, 32);
    prep_w<<<288,  256, 0, stream>>>(w3, Wt3, 128, 64);
    prep_w<<<1152, 256, 0, stream>>>(w4, Wt4, 256, 128);

    // conv1 -> raw f1; stats on raw f1 -> ss1 (conv2 folds BN into A-staging)
    conv1_direct<<<dim3(256,8), 256, 0, stream>>>(x, w1, f1b);
    bn_stats_nhwc<32><<<1024, 256, 0, stream>>>(f1b, part);
    bn_stats_final2<<<32, 256, 0, stream>>>(part, g1, b1, 32, 1024, ss1);

    conv_mfma<32,64,false><<<dim3(256,1,8), 256, 0, stream>>>(f1b, Wt2, ss1, f2b, nullptr, part);
    bn_stats_final2<<<64, 256, 0, stream>>>(part, g2, b2, 64, 2048, ss2);

    conv_mfma<64,128,false><<<dim3(256,2,8), 256, 0, stream>>>(f2b, Wt3, ss2, f3b, nullptr, part);
    bn_stats_final2<<<128, 256, 0, stream>>>(part, g3, b3, 128, 2048, ss3);

    conv_mfma<128,256,true><<<dim3(256,4,8), 256, 0, stream>>>(f3b, Wt4, ss3, rawlo, rawhi, part);
    bn_stats_final2<<<256, 256, 0, stream>>>(part, g4, b4, 256, 2048, ss4);

    // gathers read RAW f4 (+inline BN) BEFORE the expand kernels clobber raw
    gather_w_raw<<<8192, 256, 0, stream>>>(rawlo, rawhi, ss4, anc, oWA);
    gather_w_raw<<<8192, 256, 0, stream>>>(rawlo, rawhi, ss4, pos, oWP);
    gather_patch<<<4704, 256, 0, stream>>>(x, anc, oPR);

    // expand raw -> fp32 feat (transpose).  Safety by launch order:
    //  E1: b 0..4  writes feat bytes [0, 335.5MB)       (below rawlo)
    //  E2: b 5     writes [335.5, 402.7) = raw of b0,b1 (read by E1)
    //  E3: b 6,7   reads ws, writes [402.7, 537) = raw of b2..b5 (read E1/E2)
    bn_expand_t<<<5120, 256, 0, stream>>>(rawlo, rawhi, ss4, feat, 0);
    bn_expand_t<<<1024, 256, 0, stream>>>(rawlo, rawhi, ss4, feat, 5);
    bn_expand_t<<<2048, 256, 0, stream>>>(rawlo, rawhi, ss4, feat, 6);

    // mlp last: it overwrites oRC (incl. ss slots) after all consumers done
    mlp8<<<1024, 256, 0, stream>>>(oWA, l1w, l1b, l2w, l2b, oRC);
}

// Round 15
// 767.784 us; speedup vs baseline: 1.6530x; 1.0539x over previous
//
#include <hip/hip_runtime.h>
#include <hip/hip_bf16.h>

typedef unsigned short u16;
typedef short bf16x8 __attribute__((ext_vector_type(8)));
typedef float f32x4 __attribute__((ext_vector_type(4)));
typedef unsigned short u16x8 __attribute__((ext_vector_type(8)));

#define PD 147

static const long OFF_PREAL = 134217728L;
static const long OFF_PRECON= 135421952L;
static const long OFF_WA    = 136626176L;
static const long OFF_WP    = 138723328L;

// raw f4 bf16 NHWC split: elems [0,100663296) (= batches 0..5) at d_out
// u16-offset 167772160 (top 201.3MB of feat region); batches 6,7 in ws f2.
static const long RAW_SPLIT = 100663296L;

__device__ __forceinline__ float lrelu(float v){ return v >= 0.f ? v : 0.01f*v; }

__device__ __forceinline__ float bf2f(u16 u){
    union { unsigned int i; float f; } x; x.i = ((unsigned int)u) << 16; return x.f;
}
__device__ __forceinline__ u16 f2bf(float f){
    __hip_bfloat16 h = __float2bfloat16(f);
    return *reinterpret_cast<u16*>(&h);
}

__device__ __forceinline__ void gload16(const void* g, void* l){
    __builtin_amdgcn_global_load_lds((const __attribute__((address_space(1))) void*)g,
                                     (__attribute__((address_space(3))) void*)l, 16, 0, 0);
}

// ---------------------------------------------------------------------------
// MFMA implicit-GEMM 3x3 SAME conv — round-12 configuration (best measured:
// 766us total).  6 scheduling variants tried against this skeleton (counted
// vmcnt, depth-3 prefetch, BK=96, B-in-regs, T14 split, occupancy x2) — all
// regressed or null; every pipe <=40% busy, levers exhausted.
// 256 threads / 4 waves, wave tile = 64px x 64ch (acc 64 VGPR), block =
// 16x16px x 64 output ch (bz splits KOUT); ~3 blocks/CU.
// B in LDS dbuf via global_load_lds (WAVE-UNIFORM dst, m104); A
// single-buffered in LDS, reg-staged with fused BN+lrelu of the previous
// layer (identical arithmetic to a separate bn_apply pass).
// Fused deterministic BN partial stats.  Output NHWC bf16 raw; SPLIT:
// batches 0..5 -> out_, 6,7 -> rawhi.
// ---------------------------------------------------------------------------
template<int CIN, int KOUT, bool SPLIT>
__global__ __launch_bounds__(256, 3)
void conv_mfma(const u16* __restrict__ fin, const u16* __restrict__ wt,
               const float* __restrict__ ssin,
               void* __restrict__ out_, u16* __restrict__ rawhi,
               float* __restrict__ part)
{
    constexpr int CC = CIN / 32;
    constexpr int NSTEPS = CC * 9;                 // one tap per step
    constexpr int ABYTES = 324 * 32 * 2;           // single-buffered A
    constexpr int BBYTES = 2 * 64 * 32 * 2;        // dbuf B: 64ch x 32 x bf16
    constexpr int EPIB = 256 * 64 * 2;             // epilogue transpose
    constexpr int SB = (ABYTES + BBYTES) > EPIB ? (ABYTES + BBYTES) : EPIB;
    __shared__ __align__(16) char smem[SB];
    u16* As = (u16*)smem;
    u16* Bs = (u16*)(smem + ABYTES);

    const int tid = threadIdx.x;
    const int w = tid >> 6, lane = tid & 63;
    const int tile = blockIdx.x;
    const int tx0 = (tile & 15) << 4, ty0 = (tile >> 4) << 4;
    const int bz = blockIdx.y;                     // output-channel slice
    const int b  = blockIdx.z;
    const long pixbase = (long)b << 16;
    const int hi = lane >> 4;
    const int quarter = tid & 3;

    f32x4 acc[4][4];
#pragma unroll
    for (int m = 0; m < 4; m++)
#pragma unroll
        for (int n = 0; n < 4; n++) acc[m][n] = (f32x4){0.f,0.f,0.f,0.f};

    // A reg-staging: raw bf16 -> BN+lrelu -> bf16 -> per-lane ds_write.
    auto stage_a = [&](int cc){
        float sc8[8], sh8[8];
        int c0 = cc*32 + quarter*8;
#pragma unroll
        for (int j = 0; j < 8; j++){
            sc8[j] = ssin[c0 + j];
            sh8[j] = ssin[CIN + c0 + j];
        }
#pragma unroll
        for (int r = 0; r < 6; ++r){
            int q = r*256 + tid;
            if (q < 1296){
                int pf = q >> 2;
                int ly = pf / 18, lx = pf - ly*18;
                int gy = ty0 + ly - 1, gx = tx0 + lx - 1;
                u16x8 o = (u16x8){0,0,0,0,0,0,0,0};
                if ((unsigned)gy < 256u && (unsigned)gx < 256u){
                    u16x8 v = *(const u16x8*)(fin + ((pixbase + (gy<<8) + gx) * CIN + cc*32 + quarter*8));
#pragma unroll
                    for (int j = 0; j < 8; j++)
                        o[j] = f2bf(lrelu(sc8[j]*bf2f(v[j]) + sh8[j]));
                }
                *(u16x8*)(As + q*8) = o;           // halo stays zero
            }
        }
    };
    // B staging: one gload16 per thread (64ch x 4 quarters = 256 = blockDim)
    auto stage_b = [&](int s, int buf){
        int cc2 = s / 9, tap = s - cc2*9;
        const u16* src = wt + (((long)tap*KOUT + bz*64 + (tid>>2)) * CIN + cc2*32 + (tid&3)*8);
        u16* dst = Bs + buf*2048 + (w*64)*8;       // WAVE-UNIFORM base (m104)
        gload16(src, dst);
    };

    // prologue
    stage_a(0);
    stage_b(0, 0);
    __syncthreads();

#pragma unroll 1
    for (int s = 0; s < NSTEPS; ++s){
        int cc = s / 9, tap = s - cc*9;
        if (s + 1 < NSTEPS) stage_b(s + 1, (s + 1) & 1);

        int dy = tap / 3, dx = tap - dy*3;
        const u16* Bb = Bs + (s & 1) * 2048;
        bf16x8 av[4];
#pragma unroll
        for (int m = 0; m < 4; m++){
            int pf = (w*4 + m + dy)*18 + (lane & 15) + dx;
            av[m] = *(const bf16x8*)(As + pf*32 + hi*8);
        }
        bf16x8 bv[4];
#pragma unroll
        for (int n = 0; n < 4; n++){
            int chl = n*16 + (lane & 15);
            bv[n] = *(const bf16x8*)(Bb + chl*32 + hi*8);
        }
#pragma unroll
        for (int m = 0; m < 4; m++)
#pragma unroll
            for (int n = 0; n < 4; n++)
                acc[m][n] = __builtin_amdgcn_mfma_f32_16x16x32_bf16(av[m], bv[n], acc[m][n], 0, 0, 0);

        __syncthreads();   // drains vmcnt/lgkmcnt (next B ready) + readers done
        if (tap == 8 && cc + 1 < CC){
            stage_a(cc + 1);       // safe: all reads of A(cc) completed
            __syncthreads();       // A(cc+1) visible
        }
    }

    // ---- fused BN partial stats: 4 wave partials -> LDS -> 64-ch slice ----
    {
        float* sred = (float*)smem;                // [2][4][64], aliases As
#pragma unroll
        for (int n = 0; n < 4; n++){
            float s = 0.f, s2 = 0.f;
#pragma unroll
            for (int m = 0; m < 4; m++)
#pragma unroll
                for (int j = 0; j < 4; j++){
                    float v = acc[m][n][j];
                    s += v; s2 += v*v;
                }
            s += __shfl_down(s, 32); s2 += __shfl_down(s2, 32);
            s += __shfl_down(s, 16); s2 += __shfl_down(s2, 16);
            if (lane < 16){
                int ch = n*16 + lane;
                sred[w*64 + ch]       = s;
                sred[256 + w*64 + ch] = s2;
            }
        }
        __syncthreads();
        if (tid < 64){
            float S = 0.f, S2 = 0.f;
#pragma unroll
            for (int w2 = 0; w2 < 4; w2++){
                S  += sred[w2*64 + tid];
                S2 += sred[256 + w2*64 + tid];
            }
            long i = (long)b*256 + tile;
            long off = (i*KOUT + bz*64 + tid)*2;
            part[off]   = S;
            part[off+1] = S2;
        }
        __syncthreads();
    }

    // ---- epilogue: LDS transpose -> NHWC bf16 raw (64-ch slice) ----
    {
        u16* ep = (u16*)smem;
#pragma unroll
        for (int m = 0; m < 4; m++)
#pragma unroll
            for (int n = 0; n < 4; n++){
                int ch = n*16 + (lane & 15);
#pragma unroll
                for (int j = 0; j < 4; j++){
                    int px = (w*4 + m)*16 + (lane>>4)*4 + j;
                    ep[px*64 + ch] = f2bf(acc[m][n][j]);
                }
            }
        __syncthreads();
        u16* outh = (u16*)out_;
        if (SPLIT && b >= 6) outh = rawhi - RAW_SPLIT;
#pragma unroll
        for (int it = 0; it < 8; ++it){
            int i = it*256 + tid;
            int px = i >> 3, u = i & 7;
            int py = px >> 4, pxc = px & 15;
            long ga = (pixbase + ((ty0+py)<<8) + tx0 + pxc) * KOUT + bz*64 + (long)u*8;
            *(int4*)(outh + ga) = *(int4*)(ep + (long)i*8);
        }
    }
}

// ---------------------------------------------------------------------------
// conv1: 3->32 direct (tiny), output NHWC bf16 raw
// ---------------------------------------------------------------------------
__global__ __launch_bounds__(256)
void conv1_direct(const float* __restrict__ x, const float* __restrict__ w1, u16* __restrict__ f1)
{
    __shared__ float wl[864];
    const int t = threadIdx.x;
    for (int i = t; i < 864; i += 256) wl[i] = w1[i];
    __syncthreads();
    const int y = blockIdx.x, b = blockIdx.y;
    float acc[32];
#pragma unroll
    for (int k = 0; k < 32; k++) acc[k] = 0.f;
    const long ib = (long)b*3*65536;
    for (int c = 0; c < 3; c++){
#pragma unroll
        for (int dy = 0; dy < 3; dy++){
            int gy = y + dy - 1;
#pragma unroll
            for (int dx = 0; dx < 3; dx++){
                int gx = t + dx - 1;
                float v = 0.f;
                if ((unsigned)gy < 256u && (unsigned)gx < 256u)
                    v = x[ib + c*65536 + (gy<<8) + gx];
                const float* wp = &wl[c*9 + dy*3 + dx];
#pragma unroll
                for (int k = 0; k < 32; k++) acc[k] += v * wp[k*27];
            }
        }
    }
    u16 ub[32];
#pragma unroll
    for (int k = 0; k < 32; k++) ub[k] = f2bf(acc[k]);
    u16* dst = f1 + ((long)(b*65536 + (y<<8) + t)) * 32;
#pragma unroll
    for (int j = 0; j < 4; j++) *(int4*)(dst + j*8) = *(int4*)(ub + j*8);
}

// weight transpose: wt[tap][k][c] = bf16(w[k][c][tap])
__global__ __launch_bounds__(256)
void prep_w(const float* __restrict__ w, u16* __restrict__ wt, int K, int C)
{
    int i = blockIdx.x*256 + threadIdx.x;
    if (i >= 9*K*C) return;
    int c = i % C; int r = i / C; int k = r % K; int tap = r / K;
    wt[i] = f2bf(w[((long)k*C + c)*9 + tap]);
}

// ---------------------------------------------------------------------------
// BN stats over NHWC bf16 (layer 1 only)
// ---------------------------------------------------------------------------
template<int C>
__global__ __launch_bounds__(256)
void bn_stats_nhwc(const u16* __restrict__ f, float* __restrict__ part)
{
    constexpr int CQ = C/4;
    constexpr int SUBS = 256/CQ;
    const int t = threadIdx.x;
    const int cq = t & (CQ-1);
    const int sub = t / CQ;
    const long rowbase = (long)blockIdx.x * 512;
    float s[4] = {0,0,0,0}, q2[4] = {0,0,0,0};
    for (int r = sub; r < 512; r += SUBS){
        ushort4 v = *(const ushort4*)(f + (rowbase + r)*C + cq*4);
        float x0 = bf2f(v.x), x1 = bf2f(v.y), x2 = bf2f(v.z), x3 = bf2f(v.w);
        s[0]+=x0; q2[0]+=x0*x0; s[1]+=x1; q2[1]+=x1*x1;
        s[2]+=x2; q2[2]+=x2*x2; s[3]+=x3; q2[3]+=x3*x3;
    }
    __shared__ float r0[256], r1[256];
    for (int j = 0; j < 4; j++){
        r0[t] = s[j]; r1[t] = q2[j];
        __syncthreads();
        for (int st = 128; st >= CQ; st >>= 1){
            if (t < st){ r0[t] += r0[t+st]; r1[t] += r1[t+st]; }
            __syncthreads();
        }
        if (t < CQ){
            part[((long)blockIdx.x * C + t*4 + j)*2]     = r0[t];
            part[((long)blockIdx.x * C + t*4 + j)*2 + 1] = r1[t];
        }
        __syncthreads();
    }
}

__global__ __launch_bounds__(256)
void bn_stats_final2(const float* __restrict__ part, const float* __restrict__ g,
                     const float* __restrict__ bb, int C, int NB2, float* __restrict__ ss)
{
    const int c = blockIdx.x, t = threadIdx.x;
    float s = 0.f, s2 = 0.f;
    for (int i = t; i < NB2; i += 256){
        s  += part[((long)i*C + c)*2];
        s2 += part[((long)i*C + c)*2 + 1];
    }
    __shared__ float r0[256], r1[256];
    r0[t] = s; r1[t] = s2;
    __syncthreads();
    for (int st = 128; st > 0; st >>= 1){
        if (t < st){ r0[t] += r0[t+st]; r1[t] += r1[t+st]; }
        __syncthreads();
    }
    if (t == 0){
        const float invN = 1.f/524288.f;
        float m = r0[0]*invN;
        float v = r1[0]*invN - m*m;
        float sc = g[c]/sqrtf(v + 1e-5f);
        ss[c] = sc; ss[C+c] = bb[c] - m*sc;
    }
}

// ---------------------------------------------------------------------------
// f4 raw NHWC bf16 -> NCHW fp32 feat with BN+lrelu (LDS-tiled transpose).
// 64-px strip per block; 16 consecutive lanes write 16 consecutive float4s
// (256B contiguous) of one channel.
// ---------------------------------------------------------------------------
__global__ __launch_bounds__(256)
void bn_expand_t(const u16* __restrict__ rawlo, const u16* __restrict__ rawhi,
                 const float* __restrict__ ss, float* __restrict__ feat, int b0)
{
    __shared__ u16 lds[64*258];
    const int bid = blockIdx.x;
    const int b = b0 + (bid >> 10);
    const int px0 = (bid & 1023) * 64;
    const long p0 = (((long)(b<<16) + px0)) << 8;
    const u16* src = (b < 6) ? (rawlo + p0) : (rawhi + (p0 - RAW_SPLIT));
    const int t = threadIdx.x;
#pragma unroll
    for (int it = 0; it < 8; ++it){
        int i = it*256 + t;
        int px = i >> 5, u = i & 31;
        *(u16x8*)&lds[px*258 + u*8] = *(const u16x8*)(src + (long)i*8);
    }
    __syncthreads();
#pragma unroll
    for (int it = 0; it < 16; ++it){
        int idx = it*256 + t;
        int ch = idx >> 4;
        int q  = idx & 15;
        const float sc = ss[ch], sh = ss[256 + ch];
        float4 o;
        o.x = lrelu(sc*bf2f(lds[(q*4+0)*258 + ch]) + sh);
        o.y = lrelu(sc*bf2f(lds[(q*4+1)*258 + ch]) + sh);
        o.z = lrelu(sc*bf2f(lds[(q*4+2)*258 + ch]) + sh);
        o.w = lrelu(sc*bf2f(lds[(q*4+3)*258 + ch]) + sh);
        *(float4*)(feat + (((long)(b*256 + ch)) << 16) + px0 + q*4) = o;
    }
}

// ---------------------------------------------------------------------------
// gather W from raw NHWC bf16 + inline BN (matches bn_expand_t arithmetic)
// ---------------------------------------------------------------------------
__global__ __launch_bounds__(256)
void gather_w_raw(const u16* __restrict__ rawlo, const u16* __restrict__ rawhi,
                  const float* __restrict__ ss, const int* __restrict__ hw,
                  float* __restrict__ outW)
{
    const int site = blockIdx.x;
    const int b = site >> 10;
    const int y = hw[site*2], x = hw[site*2 + 1];
    const int c = threadIdx.x;
    const long p = ((long)((b<<16) + (y<<8) + x)) << 8;
    const u16* base = (b < 6) ? (rawlo + p) : (rawhi + (p - RAW_SPLIT));
    float v = bf2f(base[c]);
    outW[(long)site*256 + c] = lrelu(ss[c]*v + ss[256 + c]);
}

__global__ __launch_bounds__(256)
void gather_patch(const float* __restrict__ x, const int* __restrict__ hw,
                  float* __restrict__ out)
{
    const long i = (long)blockIdx.x*256 + threadIdx.x;
    if (i >= 1204224L) return;
    const int px = (int)(i % 7);
    long r = i / 7;
    const int py = (int)(r % 7); r /= 7;
    const int c  = (int)(r % 3); r /= 3;
    const int s  = (int)(r % 1024);
    const int b  = (int)(r / 1024);
    const int site = b*1024 + s;
    const int yy = hw[site*2]     - 3 + py;
    const int xx = hw[site*2 + 1] - 3 + px;
    out[i] = x[(((long)(b*3 + c)) << 16) + ((long)yy << 8) + xx];
}

// ---------------------------------------------------------------------------
// decoder MLP, 8 sites per block (8x weight reuse per load)
// ---------------------------------------------------------------------------
__global__ __launch_bounds__(256)
void mlp8(const float* __restrict__ Wa, const float* __restrict__ l1w,
          const float* __restrict__ l1b, const float* __restrict__ l2w,
          const float* __restrict__ l2b, float* __restrict__ out)
{
    __shared__ float wa[2048];
    __shared__ float h[8][152];
    const int blk = blockIdx.x;
    const int t = threadIdx.x;
#pragma unroll
    for (int it = 0; it < 8; ++it)
        wa[it*256 + t] = Wa[(long)blk*2048 + it*256 + t];
    __syncthreads();
    if (t < PD){
        float a[8] = {0,0,0,0,0,0,0,0};
        const float* wr = l1w + t*256;
#pragma unroll 4
        for (int l = 0; l < 256; ++l){
            float wv = wr[l];
#pragma unroll
            for (int g = 0; g < 8; ++g) a[g] += wa[g*256 + l]*wv;
        }
        float bb = l1b[t];
#pragma unroll
        for (int g = 0; g < 8; ++g) h[g][t] = lrelu(a[g] + bb);
    }
    __syncthreads();
    if (t < PD){
        float r[8] = {0,0,0,0,0,0,0,0};
        const float* wr = l2w + t*PD;
        for (int p = 0; p < PD; ++p){
            float wv = wr[p];
#pragma unroll
            for (int g = 0; g < 8; ++g) r[g] += h[g][p]*wv;
        }
        float bb = l2b[t];
#pragma unroll
        for (int g = 0; g < 8; ++g)
            out[((long)(blk*8 + g))*PD + t] = r[g] + bb;
    }
}

extern "C" void kernel_launch(void* const* d_in, const int* in_sizes, int n_in,
                              void* d_out, int out_size, void* d_ws, size_t ws_size,
                              hipStream_t stream)
{
    const float* x   = (const float*)d_in[0];
    const int*   anc = (const int*)  d_in[1];
    const int*   pos = (const int*)  d_in[2];
    const float* w1  = (const float*)d_in[3];
    const float* g1  = (const float*)d_in[4];
    const float* b1  = (const float*)d_in[5];
    const float* w2  = (const float*)d_in[6];
    const float* g2  = (const float*)d_in[7];
    const float* b2  = (const float*)d_in[8];
    const float* w3  = (const float*)d_in[9];
    const float* g3  = (const float*)d_in[10];
    const float* b3  = (const float*)d_in[11];
    const float* w4  = (const float*)d_in[12];
    const float* g4  = (const float*)d_in[13];
    const float* b4  = (const float*)d_in[14];
    const float* l1w = (const float*)d_in[15];
    const float* l1b = (const float*)d_in[16];
    const float* l2w = (const float*)d_in[17];
    const float* l2b = (const float*)d_in[18];

    float* feat = (float*)d_out;
    float* oPR  = feat + OFF_PREAL;
    float* oRC  = feat + OFF_PRECON;
    float* oWA  = feat + OFF_WA;
    float* oWP  = feat + OFF_WP;

    // ws: f2 [0,64MB), f3 [64MB,192MB), f1 [128MB,160MB) (inside f3, dead before conv3)
    char* wsb = (char*)d_ws;
    u16* f2b = (u16*)wsb;
    u16* f3b = (u16*)(wsb + 67108864L);
    u16* f1b = (u16*)(wsb + 134217728L);

    // raw f4 bf16 NHWC: batches 0..5 in top of feat region; 6,7 in f2 region
    u16* rawlo = (u16*)d_out + 167772160L;    // byte offset 335544320
    u16* rawhi = f2b;                          // f2 dead after conv3

    // scratch inside d_out regions only written by later kernels
    u16* Wt2 = (u16*)oWA;                      // dead after conv2
    u16* Wt3 = Wt2 + 18432;                    // dead after conv3
    u16* Wt4 = Wt3 + 73728;                    // dead after conv4
    float* part = oWP;                         // 2048*256*2 floats max = 4MB
    float* ss1 = oRC, *ss2 = oRC + 64, *ss3 = oRC + 192, *ss4 = oRC + 448;  // dead before mlp8

    prep_w<<<72,   256, 0, stream>>>(w2, Wt2, 64, 32);
    prep_w<<<288,  256, 0, stream>>>(w3, Wt3, 128, 64);
    prep_w<<<1152, 256, 0, stream>>>(w4, Wt4, 256, 128);

    // conv1 -> raw f1; stats on raw f1 -> ss1 (conv2 folds BN into A-staging)
    conv1_direct<<<dim3(256,8), 256, 0, stream>>>(x, w1, f1b);
    bn_stats_nhwc<32><<<1024, 256, 0, stream>>>(f1b, part);
    bn_stats_final2<<<32, 256, 0, stream>>>(part, g1, b1, 32, 1024, ss1);

    conv_mfma<32,64,false><<<dim3(256,1,8), 256, 0, stream>>>(f1b, Wt2, ss1, f2b, nullptr, part);
    bn_stats_final2<<<64, 256, 0, stream>>>(part, g2, b2, 64, 2048, ss2);

    conv_mfma<64,128,false><<<dim3(256,2,8), 256, 0, stream>>>(f2b, Wt3, ss2, f3b, nullptr, part);
    bn_stats_final2<<<128, 256, 0, stream>>>(part, g3, b3, 128, 2048, ss3);

    conv_mfma<128,256,true><<<dim3(256,4,8), 256, 0, stream>>>(f3b, Wt4, ss3, rawlo, rawhi, part);
    bn_stats_final2<<<256, 256, 0, stream>>>(part, g4, b4, 256, 2048, ss4);

    // gathers read RAW f4 (+inline BN) BEFORE the expand kernels clobber raw
    gather_w_raw<<<8192, 256, 0, stream>>>(rawlo, rawhi, ss4, anc, oWA);
    gather_w_raw<<<8192, 256, 0, stream>>>(rawlo, rawhi, ss4, pos, oWP);
    gather_patch<<<4704, 256, 0, stream>>>(x, anc, oPR);

    // expand raw -> fp32 feat (transpose).  Safety by launch order:
    //  E1: b 0..4  writes feat bytes [0, 335.5MB)       (below rawlo)
    //  E2: b 5     writes [335.5, 402.7) = raw of b0,b1 (read by E1)
    //  E3: b 6,7   reads ws, writes [402.7, 537) = raw of b2..b5 (read E1/E2)
    bn_expand_t<<<5120, 256, 0, stream>>>(rawlo, rawhi, ss4, feat, 0);
    bn_expand_t<<<1024, 256, 0, stream>>>(rawlo, rawhi, ss4, feat, 5);
    bn_expand_t<<<2048, 256, 0, stream>>>(rawlo, rawhi, ss4, feat, 6);

    // mlp last: it overwrites oRC (incl. ss slots) after all consumers done
    mlp8<<<1024, 256, 0, stream>>>(oWA, l1w, l1b, l2w, l2b, oRC);
}